// Round 15
// baseline (431.906 us; speedup 1.0000x reference)
//
#include <hip/hip_runtime.h>

typedef __attribute__((ext_vector_type(8))) _Float16 half8;
typedef __attribute__((ext_vector_type(16))) float f32x16;

static __device__ const int d_LENS[14] = {4,3,2,1,2,3,2,3,2,1,1,3,2,3};
static __device__ const int d_RIDX[14][4] = {
  {0,1,16,17},{2,18,19,19},{3,4,4,4},{20,20,20,20},{7,8,8,8},{21,25,26,26},
  {5,22,22,22},{6,23,24,24},{9,27,27,27},{11,11,11,11},{29,29,29,29},
  {10,15,28,28},{12,30,30,30},{13,14,31,31}};

// Work-balanced XCD map: each XCD gets exactly 256 block-len units (64 btiles of 128 rows).
static __device__ const int d_nTot[8] = {64,96,96,128,128,128,128,128};
static __device__ const int d_regA[8] = {0,1,5,7,11,13,2,6};
static __device__ const int d_regB[8] = {0,12,12,3,9,10,4,8};
static __device__ const int d_boff[8] = {0,0,32,0,0,0,0,0};

__device__ __forceinline__ float sigf(float v){
  return __builtin_amdgcn_rcpf(1.0f + __expf(-v));
}
__device__ __forceinline__ float tanhf2(float v){
  return 1.0f - 2.0f*__builtin_amdgcn_rcpf(1.0f + __expf(2.0f*v));
}

__device__ __forceinline__ void gload16(const void* g, void* l){
  __builtin_amdgcn_global_load_lds((const __attribute__((address_space(1))) void*)g,
                                   (__attribute__((address_space(3))) void*)l, 16, 0, 0);
}

// Stage one 64KB fragment-ordered weight chunk into LDS, purely linear.
__device__ __forceinline__ void stage_chunk(const _Float16* __restrict__ base, int ci,
                                            char* wb, int tid){
  const char* src = (const char*)base + (size_t)ci*65536;
  #pragma unroll
  for (int i=0;i<8;i++){
    int L = i*8192 + tid*16;
    gload16(src + L, wb + L);
  }
}

// ---------------------------------------------------------------------------
// prep_w: f32 -> f16 weights in MFMA FRAGMENT ORDER:
// B-frag (chunk ci, u, g, ks, lane) = 16B at elems ci*32768+u*16384+(g*8+ks)*512+lane*8
// ---------------------------------------------------------------------------
__global__ void prep_w(const float* __restrict__ w_ih, const float* __restrict__ w_hh,
                       const float* __restrict__ b_ih, const float* __restrict__ b_hh,
                       _Float16* __restrict__ wih, _Float16* __restrict__ whh,
                       float* __restrict__ bias)
{
  int tid = blockIdx.x*256 + threadIdx.x;
  if (tid < 458752){
    int a = (tid >= 229376);
    const float* src = a ? w_hh : w_ih;
    _Float16* dst    = a ? whh  : wih;
    int t = (a ? (tid - 229376) : tid) * 8;
    int l  = (t>>3)&63, ks=(t>>9)&7, g=(t>>12)&3, uu=(t>>14)&1, c=(t>>15)&1, rd=t>>16;
    int v = l&31, q = l>>5;
    int n  = g*128 + c*64 + uu*32 + v;
    int k0 = q*8 + ks*16;
    const float* s = src + (size_t)rd*65536 + n*128 + k0;
    float4 a0 = *(const float4*)s;
    float4 a1 = *(const float4*)(s+4);
    half8 h;
    h[0]=(_Float16)a0.x; h[1]=(_Float16)a0.y; h[2]=(_Float16)a0.z; h[3]=(_Float16)a0.w;
    h[4]=(_Float16)a1.x; h[5]=(_Float16)a1.y; h[6]=(_Float16)a1.z; h[7]=(_Float16)a1.w;
    *(half8*)(dst + t) = h;
  } else {
    int t = tid - 458752;
    if (t < 14336){
      int rd = t >> 9, np = t & 511;
      int c = (np >> 8) & 1, uu = (np >> 7) & 1, g = (np >> 5) & 3, vv = np & 31;
      int n = g*128 + c*64 + uu*32 + vv;
      bias[t] = b_ih[rd*512 + n] + b_hh[rd*512 + n];
    }
  }
}

// ---------------------------------------------------------------------------
// prep_x: f32 x -> f16 in A-FRAGMENT-LINEAR order for 128-row btiles:
// frag f = (((bt*32 + chan)*4 + wr)*8 + ks)*64 + lane, 8 elems at f*8.
// Source: row = bt*128 + wr*32 + (lane&31), k = (lane>>5)*8 + ks*16 + j.
// ---------------------------------------------------------------------------
__global__ void prep_x(const float* __restrict__ x, _Float16* __restrict__ x16)
{
  size_t i8 = (size_t)blockIdx.x*256 + threadIdx.x;   // 4,194,304 frags
  int l    = (int)(i8 & 63);
  int ks   = (int)((i8 >> 6) & 7);
  int wr   = (int)((i8 >> 9) & 3);
  int chan = (int)((i8 >> 11) & 31);
  size_t bt = i8 >> 16;
  int row = (int)(bt*128) + wr*32 + (l & 31);
  int k0  = (l >> 5)*8 + ks*16;
  const float* s = x + ((size_t)row*32 + chan)*128 + k0;
  float4 a0 = *(const float4*)s;
  float4 a1 = *(const float4*)(s+4);
  half8 h;
  h[0]=(_Float16)a0.x; h[1]=(_Float16)a0.y; h[2]=(_Float16)a0.z; h[3]=(_Float16)a0.w;
  h[4]=(_Float16)a1.x; h[5]=(_Float16)a1.y; h[6]=(_Float16)a1.z; h[7]=(_Float16)a1.w;
  *(half8*)(x16 + i8*8) = h;
}

// ---------------------------------------------------------------------------
// Main kernel (R14 minus persistent xa regs; SB after EVERY step).
// Block = (region r, 128 batch rows), 512 thr / 8 waves; wr=wv>>1, u=wv&1.
// Weights LDS-staged per 64KB chunk (fragment-linear); h in XOR-swizzled dbuf.
// A-frags loaded on demand from frag-linear x16 (1KB/wave, L1/L2-hot reuse).
// Live arch-VGPR demand ~100 < the allocator's 128 -> no spill traffic.
// ---------------------------------------------------------------------------
template<int XMODE, int F16OUT>
__global__ __launch_bounds__(512, 1) void lstm_k(
    const float* __restrict__ xf32, const _Float16* __restrict__ x16,
    const _Float16* __restrict__ wih, const _Float16* __restrict__ whh,
    const float* __restrict__ bias,
    _Float16* __restrict__ hout, float* __restrict__ fout,
    float* __restrict__ part)
{
  __shared__ char wb[65536];
  __shared__ char hb0[65536];
  __shared__ float red[16];

  const int tid  = threadIdx.x;
  const int lane = tid & 63;
  const int wv = tid >> 6;
  const int wr = wv >> 1;
  const int u  = wv & 1;
  const int v  = lane & 31;
  const int q  = lane >> 5;

  const int xcd = blockIdx.x & 7;
  const int kk  = blockIdx.x >> 3;
  if (kk >= d_nTot[xcd]) return;
  int r, bt;
  if (kk < 64){ r = d_regA[xcd]; bt = kk; }
  else        { r = d_regB[xcd]; bt = d_boff[xcd] + (kk - 64); }
  const int b0 = bt << 7;
  const int len = d_LENS[r];

  float bf[2][4];
  #pragma unroll
  for (int c=0;c<2;c++)
    #pragma unroll
    for (int g=0;g<4;g++)
      bf[c][g] = bias[(size_t)r*1024 + c*256 + u*128 + g*32 + v];

  float cst[2][16];
  #pragma unroll
  for (int c=0;c<2;c++)
    #pragma unroll
    for (int e=0;e<16;e++) cst[c][e] = 0.0f;

  float lsum = 0.0f, lsq = 0.0f;
  const int hrow = wr*32 + v;
  char* const wp = wb + ((u*32)<<10) + (lane<<4);   // this wave's B-frag base
  const _Float16* xp = x16;                          // set per timestep
  const float* xbf = xf32;                           // fallback path base

#define SB() __builtin_amdgcn_sched_barrier(0)
// x-GEMM step: A-frag loaded on demand from frag-linear x16.
#define GXS(KS) { \
    half8 ax = *(const half8*)(xp + KS*512); \
    half8 b0 = *(const half8*)(wp + ((0*8+KS)<<10)); \
    half8 b1 = *(const half8*)(wp + ((1*8+KS)<<10)); \
    half8 b2 = *(const half8*)(wp + ((2*8+KS)<<10)); \
    half8 b3 = *(const half8*)(wp + ((3*8+KS)<<10)); \
    acc0 = __builtin_amdgcn_mfma_f32_32x32x16_f16(ax, b0, acc0, 0,0,0); \
    acc1 = __builtin_amdgcn_mfma_f32_32x32x16_f16(ax, b1, acc1, 0,0,0); \
    acc2 = __builtin_amdgcn_mfma_f32_32x32x16_f16(ax, b2, acc2, 0,0,0); \
    acc3 = __builtin_amdgcn_mfma_f32_32x32x16_f16(ax, b3, acc3, 0,0,0); } SB();
// x-GEMM step, f32 fallback.
#define GXF(KS) { \
    float4 a0 = *(const float4*)(xbf + KS*16); \
    float4 a1 = *(const float4*)(xbf + KS*16 + 4); \
    half8 ax; \
    ax[0]=(_Float16)a0.x; ax[1]=(_Float16)a0.y; ax[2]=(_Float16)a0.z; ax[3]=(_Float16)a0.w; \
    ax[4]=(_Float16)a1.x; ax[5]=(_Float16)a1.y; ax[6]=(_Float16)a1.z; ax[7]=(_Float16)a1.w; \
    half8 b0 = *(const half8*)(wp + ((0*8+KS)<<10)); \
    half8 b1 = *(const half8*)(wp + ((1*8+KS)<<10)); \
    half8 b2 = *(const half8*)(wp + ((2*8+KS)<<10)); \
    half8 b3 = *(const half8*)(wp + ((3*8+KS)<<10)); \
    acc0 = __builtin_amdgcn_mfma_f32_32x32x16_f16(ax, b0, acc0, 0,0,0); \
    acc1 = __builtin_amdgcn_mfma_f32_32x32x16_f16(ax, b1, acc1, 0,0,0); \
    acc2 = __builtin_amdgcn_mfma_f32_32x32x16_f16(ax, b2, acc2, 0,0,0); \
    acc3 = __builtin_amdgcn_mfma_f32_32x32x16_f16(ax, b3, acc3, 0,0,0); } SB();
#define XGEMM() { if (XMODE){ GXS(0) GXS(1) GXS(2) GXS(3) GXS(4) GXS(5) GXS(6) GXS(7) } \
                  else      { GXF(0) GXF(1) GXF(2) GXF(3) GXF(4) GXF(5) GXF(6) GXF(7) } }
#define HXS(KS) { \
    half8 ah = *(const half8*)(hbr + ((hrow*256 + KS*32 + q*16) ^ ((hrow&15)<<4))); \
    half8 b0 = *(const half8*)(wp + ((0*8+KS)<<10)); \
    half8 b1 = *(const half8*)(wp + ((1*8+KS)<<10)); \
    half8 b2 = *(const half8*)(wp + ((2*8+KS)<<10)); \
    half8 b3 = *(const half8*)(wp + ((3*8+KS)<<10)); \
    acc0 = __builtin_amdgcn_mfma_f32_32x32x16_f16(ah, b0, acc0, 0,0,0); \
    acc1 = __builtin_amdgcn_mfma_f32_32x32x16_f16(ah, b1, acc1, 0,0,0); \
    acc2 = __builtin_amdgcn_mfma_f32_32x32x16_f16(ah, b2, acc2, 0,0,0); \
    acc3 = __builtin_amdgcn_mfma_f32_32x32x16_f16(ah, b3, acc3, 0,0,0); } SB();

  for (int t=0; t<len; ++t){
    const int chan = d_RIDX[r][t];
    if (XMODE) xp  = x16 + (((size_t)bt*32 + chan)*4 + wr)*4096 + lane*8;
    else       xbf = xf32 + (((size_t)(b0 + wr*32 + v))*32 + chan)*128 + q*8;
    const bool last = (t == len-1);
    char* hbr = hb0 + (((t+1)&1) << 15);   // read buf (written at t-1)
    char* hbw = hb0 + ((t&1) << 15);       // write buf for this step

    #pragma unroll
    for (int c=0;c<2;c++){
      f32x16 acc0, acc1, acc2, acc3;
      #pragma unroll
      for (int e=0;e<16;e++){
        acc0[e] = bf[c][0]; acc1[e] = bf[c][1];
        acc2[e] = bf[c][2]; acc3[e] = bf[c][3];
      }

      // ---- x_t * W_ih : stage chunk, MFMA from LDS ----
      __syncthreads();                         // prior wb reads done
      stage_chunk(wih, r*4 + c, wb, tid);
      __syncthreads();                         // staged data visible
      XGEMM()
      // ---- h_{t-1} * W_hh ----
      if (t > 0){
        __syncthreads();
        stage_chunk(whh, r*4 + c, wb, tid);
        __syncthreads();
        HXS(0) HXS(1) HXS(2) HXS(3)
        HXS(4) HXS(5) HXS(6) HXS(7)
      }
      // ---- pointwise for this chunk's 32 h-cols; h always to LDS ----
      const int ccol = c*64 + u*32 + v;
      #pragma unroll
      for (int e=0;e<16;e++){
        float iv = acc0[e], fv = acc1[e];
        float gv = acc2[e], ov = acc3[e];
        float cn = sigf(iv)*tanhf2(gv) + sigf(fv)*cst[c][e];
        cst[c][e] = cn;
        float hv = sigf(ov)*tanhf2(cn);
        _Float16 hh = (_Float16)hv;
        int rl = wr*32 + (e&3) + ((e>>2)<<3) + (q<<2);
        *(_Float16*)(hbw + ((rl*256 + ccol*2) ^ ((rl&15)<<4))) = hh;
        if (last){
          float hr = (float)hh;
          lsum += hr; lsq += hr*hr;
        }
      }
    }
  }

  // ---- backward cell: h0=c0=0 -> gates = x_last*W_ih[:,1] + b ----
  {
    char* hbk = hb0 + ((len&1) << 15);       // the non-final-fwd buffer
    const int chan = d_RIDX[r][len-1];
    if (XMODE) xp  = x16 + (((size_t)bt*32 + chan)*4 + wr)*4096 + lane*8;
    else       xbf = xf32 + (((size_t)(b0 + wr*32 + v))*32 + chan)*128 + q*8;
    #pragma unroll
    for (int c=0;c<2;c++){
      f32x16 acc0, acc1, acc2, acc3;
      {
        float g0 = bias[(size_t)r*1024 + 512 + c*256 + u*128 + 0*32 + v];
        float g1 = bias[(size_t)r*1024 + 512 + c*256 + u*128 + 1*32 + v];
        float g2 = bias[(size_t)r*1024 + 512 + c*256 + u*128 + 2*32 + v];
        float g3 = bias[(size_t)r*1024 + 512 + c*256 + u*128 + 3*32 + v];
        #pragma unroll
        for (int e=0;e<16;e++){
          acc0[e] = g0; acc1[e] = g1; acc2[e] = g2; acc3[e] = g3;
        }
      }
      __syncthreads();                       // last h-GEMM reads of hbk done
      stage_chunk(wih, r*4 + 2 + c, wb, tid);
      __syncthreads();
      XGEMM()
      const int ccol = c*64 + u*32 + v;
      #pragma unroll
      for (int e=0;e<16;e++){
        float iv = acc0[e];
        float gv = acc2[e], ov = acc3[e];
        float cn = sigf(iv)*tanhf2(gv);
        float hv = sigf(ov)*tanhf2(cn);
        _Float16 hh = (_Float16)hv;
        int rl = wr*32 + (e&3) + ((e>>2)<<3) + (q<<2);
        *(_Float16*)(hbk + ((rl*256 + ccol*2) ^ ((rl&15)<<4))) = hh;
        float hr = (float)hh;
        lsum += hr; lsq += hr*hr;
      }
    }
  }
#undef GXS
#undef GXF
#undef XGEMM
#undef HXS
#undef SB

  // ---- coalesced copy-out of fwd (hf) and bwd (hbk) h tiles ----
  __syncthreads();
  {
    const char* hf  = hb0 + (((len-1)&1) << 15);
    const char* hbk = hb0 + ((len&1) << 15);
    #pragma unroll
    for (int i=0;i<4;i++){
      int row = (tid>>4) + i*32;
      int bo  = (tid&15)*16;
      int lp  = row*256 + (bo ^ ((row&15)<<4));
      uint4 df = *(const uint4*)(hf + lp);
      uint4 db = *(const uint4*)(hbk + lp);
      size_t ob = ((size_t)(b0+row)*14 + r)*256;    // elems
      if (F16OUT){
        *(uint4*)((char*)hout + ob*2 + bo)       = df;   // fwd: bytes [0,256)
        *(uint4*)((char*)hout + ob*2 + 256 + bo) = db;   // bwd: bytes [256,512)
      } else {
        const _Float16* pf = (const _Float16*)&df;
        const _Float16* pb = (const _Float16*)&db;
        float* of  = fout + ob + (bo>>1);
        float* obw = fout + ob + 128 + (bo>>1);
        float4 o0, o1;
        o0.x=(float)pf[0]; o0.y=(float)pf[1]; o0.z=(float)pf[2]; o0.w=(float)pf[3];
        o1.x=(float)pf[4]; o1.y=(float)pf[5]; o1.z=(float)pf[6]; o1.w=(float)pf[7];
        *(float4*)of = o0; *(float4*)(of+4) = o1;
        o0.x=(float)pb[0]; o0.y=(float)pb[1]; o0.z=(float)pb[2]; o0.w=(float)pb[3];
        o1.x=(float)pb[4]; o1.y=(float)pb[5]; o1.z=(float)pb[6]; o1.w=(float)pb[7];
        *(float4*)obw = o0; *(float4*)(obw+4) = o1;
      }
    }
  }

  // ---- per-block partials ----
  #pragma unroll
  for (int off=32; off>0; off>>=1){
    lsum += __shfl_down(lsum, off);
    lsq  += __shfl_down(lsq, off);
  }
  __syncthreads();
  if (lane == 0){ red[wv] = lsum; red[8+wv] = lsq; }
  __syncthreads();
  if (tid == 0){
    float s = 0.0f, s2 = 0.0f;
    #pragma unroll
    for (int ww=0;ww<8;ww++){ s += red[ww]; s2 += red[8+ww]; }
    part[((size_t)r*64 + bt)*2]     = s;
    part[((size_t)r*64 + bt)*2 + 1] = s2;
  }
}

// ---------------------------------------------------------------------------
__global__ void stats_k(const float* __restrict__ part, const float* __restrict__ gamma,
                        const float* __restrict__ beta, float* __restrict__ stat)
{
  int r = blockIdx.x, l = threadIdx.x;
  float s  = part[((size_t)r*64 + l)*2];
  float s2 = part[((size_t)r*64 + l)*2 + 1];
  #pragma unroll
  for (int off=32; off>0; off>>=1){ s += __shfl_down(s, off); s2 += __shfl_down(s2, off); }
  if (l == 0){
    const float cnt = 2097152.0f;
    float m = s / cnt;
    float var = s2 / cnt - m*m;
    float rstd = rsqrtf(var + 1e-5f);
    float sc = gamma[r]*rstd;
    stat[r*2]   = sc;
    stat[r*2+1] = beta[r] - m*sc;
  }
}

__global__ void apply_f16(const _Float16* __restrict__ hst, const float* __restrict__ stat,
                          float* __restrict__ out)
{
  size_t i8 = (size_t)blockIdx.x*256 + threadIdx.x;
  uint4 vv = *(const uint4*)(hst + i8*8);
  int r = (int)((i8 >> 5) % 14);
  float sc = stat[r*2], sh = stat[r*2+1];
  const _Float16* hp = (const _Float16*)&vv;
  float4 o0, o1;
  o0.x = (float)hp[0]*sc + sh; o0.y = (float)hp[1]*sc + sh;
  o0.z = (float)hp[2]*sc + sh; o0.w = (float)hp[3]*sc + sh;
  o1.x = (float)hp[4]*sc + sh; o1.y = (float)hp[5]*sc + sh;
  o1.z = (float)hp[6]*sc + sh; o1.w = (float)hp[7]*sc + sh;
  ((float4*)out)[i8*2]     = o0;
  ((float4*)out)[i8*2 + 1] = o1;
}

__global__ void apply_f32(float* __restrict__ out, const float* __restrict__ stat)
{
  size_t idx = (size_t)blockIdx.x*256 + threadIdx.x;
  float4* p = (float4*)out + idx;
  float4 vv = *p;
  int r = (int)((idx >> 6) % 14);
  float sc = stat[r*2], sh = stat[r*2+1];
  vv.x = vv.x*sc + sh; vv.y = vv.y*sc + sh; vv.z = vv.z*sc + sh; vv.w = vv.w*sc + sh;
  *p = vv;
}

// ---------------------------------------------------------------------------
extern "C" void kernel_launch(void* const* d_in, const int* in_sizes, int n_in,
                              void* d_out, int out_size, void* d_ws, size_t ws_size,
                              hipStream_t stream)
{
  const float* x     = (const float*)d_in[0];
  const float* w_ih  = (const float*)d_in[1];
  const float* w_hh  = (const float*)d_in[2];
  const float* b_ih  = (const float*)d_in[3];
  const float* b_hh  = (const float*)d_in[4];
  const float* gamma = (const float*)d_in[5];
  const float* beta  = (const float*)d_in[6];
  float* out = (float*)d_out;

  const size_t HS = 29360128;               // h elements (B*14*256)
  const size_t XS = 33554432;               // x elements (B*32*128)
  const size_t wbytes = (size_t)1835008*2;  // one weight array, bytes
  const size_t tail = (14336 + 1792 + 28)*4;
  const size_t need_full = XS*2 + HS*2 + 2*wbytes + tail;   // ~138 MB

  char* wsp = (char*)d_ws;
  int full = (ws_size >= need_full) ? 1 : 0;

  _Float16* x16p; _Float16* hstore; _Float16* wihp;
  if (full){
    x16p   = (_Float16*)wsp;
    hstore = (_Float16*)(wsp + XS*2);
    wihp   = (_Float16*)(wsp + XS*2 + HS*2);
  } else {
    x16p   = (_Float16*)wsp;  // unused
    hstore = (_Float16*)wsp;  // unused
    wihp   = (_Float16*)wsp;
  }
  _Float16* whhp = wihp + 1835008;
  float* biasp = (float*)(whhp + 1835008);
  float* partp = biasp + 14336;
  float* statp = partp + 1792;

  prep_w<<<1848, 256, 0, stream>>>(w_ih, w_hh, b_ih, b_hh, wihp, whhp, biasp);
  if (full){
    prep_x<<<16384, 256, 0, stream>>>(x, x16p);
    lstm_k<1,1><<<1024, 512, 0, stream>>>(x, x16p, wihp, whhp, biasp,
                                          hstore, out, partp);
  } else {
    lstm_k<0,0><<<1024, 512, 0, stream>>>(x, x16p, wihp, whhp, biasp,
                                          hstore, out, partp);
  }
  stats_k<<<14, 64, 0, stream>>>(partp, gamma, beta, statp);
  if (full)
    apply_f16<<<14336, 256, 0, stream>>>(hstore, statp, out);
  else
    apply_f32<<<28672, 256, 0, stream>>>(out, statp);
}

// Round 16
// 391.598 us; speedup vs baseline: 1.1029x; 1.1029x over previous
//
#include <hip/hip_runtime.h>

typedef __attribute__((ext_vector_type(8))) _Float16 half8;
typedef __attribute__((ext_vector_type(16))) float f32x16;

static __device__ const int d_LENS[14] = {4,3,2,1,2,3,2,3,2,1,1,3,2,3};
static __device__ const int d_RIDX[14][4] = {
  {0,1,16,17},{2,18,19,19},{3,4,4,4},{20,20,20,20},{7,8,8,8},{21,25,26,26},
  {5,22,22,22},{6,23,24,24},{9,27,27,27},{11,11,11,11},{29,29,29,29},
  {10,15,28,28},{12,30,30,30},{13,14,31,31}};

// Work-balanced XCD map: each XCD gets exactly 256 block-len units (64 btiles of 128 rows).
static __device__ const int d_nTot[8] = {64,96,96,128,128,128,128,128};
static __device__ const int d_regA[8] = {0,1,5,7,11,13,2,6};
static __device__ const int d_regB[8] = {0,12,12,3,9,10,4,8};
static __device__ const int d_boff[8] = {0,0,32,0,0,0,0,0};

__device__ __forceinline__ float sigf(float v){
  return __builtin_amdgcn_rcpf(1.0f + __expf(-v));
}
__device__ __forceinline__ float tanhf2(float v){
  return 1.0f - 2.0f*__builtin_amdgcn_rcpf(1.0f + __expf(2.0f*v));
}

__device__ __forceinline__ void gload16(const void* g, void* l){
  __builtin_amdgcn_global_load_lds((const __attribute__((address_space(1))) void*)g,
                                   (__attribute__((address_space(3))) void*)l, 16, 0, 0);
}

// Stage one 64KB fragment-ordered weight chunk into LDS, purely linear.
__device__ __forceinline__ void stage_chunk(const _Float16* __restrict__ base, int ci,
                                            char* wb, int tid){
  const char* src = (const char*)base + (size_t)ci*65536;
  #pragma unroll
  for (int i=0;i<8;i++){
    int L = i*8192 + tid*16;
    gload16(src + L, wb + L);
  }
}

// ---------------------------------------------------------------------------
// prep_w: f32 -> f16 weights in MFMA FRAGMENT ORDER:
// B-frag (chunk ci, u, g, ks, lane) = 16B at elems ci*32768+u*16384+(g*8+ks)*512+lane*8
// ---------------------------------------------------------------------------
__global__ void prep_w(const float* __restrict__ w_ih, const float* __restrict__ w_hh,
                       const float* __restrict__ b_ih, const float* __restrict__ b_hh,
                       _Float16* __restrict__ wih, _Float16* __restrict__ whh,
                       float* __restrict__ bias)
{
  int tid = blockIdx.x*256 + threadIdx.x;
  if (tid < 458752){
    int a = (tid >= 229376);
    const float* src = a ? w_hh : w_ih;
    _Float16* dst    = a ? whh  : wih;
    int t = (a ? (tid - 229376) : tid) * 8;
    int l  = (t>>3)&63, ks=(t>>9)&7, g=(t>>12)&3, uu=(t>>14)&1, c=(t>>15)&1, rd=t>>16;
    int v = l&31, q = l>>5;
    int n  = g*128 + c*64 + uu*32 + v;
    int k0 = q*8 + ks*16;
    const float* s = src + (size_t)rd*65536 + n*128 + k0;
    float4 a0 = *(const float4*)s;
    float4 a1 = *(const float4*)(s+4);
    half8 h;
    h[0]=(_Float16)a0.x; h[1]=(_Float16)a0.y; h[2]=(_Float16)a0.z; h[3]=(_Float16)a0.w;
    h[4]=(_Float16)a1.x; h[5]=(_Float16)a1.y; h[6]=(_Float16)a1.z; h[7]=(_Float16)a1.w;
    *(half8*)(dst + t) = h;
  } else {
    int t = tid - 458752;
    if (t < 14336){
      int rd = t >> 9, np = t & 511;
      int c = (np >> 8) & 1, uu = (np >> 7) & 1, g = (np >> 5) & 3, vv = np & 31;
      int n = g*128 + c*64 + uu*32 + vv;
      bias[t] = b_ih[rd*512 + n] + b_hh[rd*512 + n];
    }
  }
}

// ---------------------------------------------------------------------------
// prep_x: f32 x -> f16 in A-FRAGMENT-LINEAR order for 128-row btiles:
// frag f = (((bt*32 + chan)*4 + wr)*8 + ks)*64 + lane, 8 elems at f*8.
// ---------------------------------------------------------------------------
__global__ void prep_x(const float* __restrict__ x, _Float16* __restrict__ x16)
{
  size_t i8 = (size_t)blockIdx.x*256 + threadIdx.x;   // 4,194,304 frags
  int l    = (int)(i8 & 63);
  int ks   = (int)((i8 >> 6) & 7);
  int wr   = (int)((i8 >> 9) & 3);
  int chan = (int)((i8 >> 11) & 31);
  size_t bt = i8 >> 16;
  int row = (int)(bt*128) + wr*32 + (l & 31);
  int k0  = (l >> 5)*8 + ks*16;
  const float* s = x + ((size_t)row*32 + chan)*128 + k0;
  float4 a0 = *(const float4*)s;
  float4 a1 = *(const float4*)(s+4);
  half8 h;
  h[0]=(_Float16)a0.x; h[1]=(_Float16)a0.y; h[2]=(_Float16)a0.z; h[3]=(_Float16)a0.w;
  h[4]=(_Float16)a1.x; h[5]=(_Float16)a1.y; h[6]=(_Float16)a1.z; h[7]=(_Float16)a1.w;
  *(half8*)(x16 + i8*8) = h;
}

// ---------------------------------------------------------------------------
// Main kernel: R14 + DEFERRED-POINTWISE overlap. Each pointwise runs inside the
// NEXT phase's stage window (after global_load_lds issue, before the drain
// barrier) so its ~600 VALU cycles hide stage latency. Writes stay >=2
// barriers ahead of readers. acc registers persist across the deferral.
// ---------------------------------------------------------------------------
template<int XMODE, int F16OUT>
__global__ __launch_bounds__(512, 1) void lstm_k(
    const float* __restrict__ xf32, const _Float16* __restrict__ x16,
    const _Float16* __restrict__ wih, const _Float16* __restrict__ whh,
    const float* __restrict__ bias,
    _Float16* __restrict__ hout, float* __restrict__ fout,
    float* __restrict__ part)
{
  __shared__ char wb[65536];
  __shared__ char hb0[65536];
  __shared__ float red[16];

  const int tid  = threadIdx.x;
  const int lane = tid & 63;
  const int wv = tid >> 6;
  const int wr = wv >> 1;
  const int u  = wv & 1;
  const int v  = lane & 31;
  const int q  = lane >> 5;

  const int xcd = blockIdx.x & 7;
  const int kk  = blockIdx.x >> 3;
  if (kk >= d_nTot[xcd]) return;
  int r, bt;
  if (kk < 64){ r = d_regA[xcd]; bt = kk; }
  else        { r = d_regB[xcd]; bt = d_boff[xcd] + (kk - 64); }
  const int b0 = bt << 7;
  const int len = d_LENS[r];

  float bf[2][4];
  #pragma unroll
  for (int c=0;c<2;c++)
    #pragma unroll
    for (int g=0;g<4;g++)
      bf[c][g] = bias[(size_t)r*1024 + c*256 + u*128 + g*32 + v];

  float cst[2][16];
  #pragma unroll
  for (int c=0;c<2;c++)
    #pragma unroll
    for (int e=0;e<16;e++) cst[c][e] = 0.0f;

  half8 xa0,xa1,xa2,xa3,xa4,xa5,xa6,xa7;
  f32x16 acc0, acc1, acc2, acc3;            // persist across deferral
  float lsum = 0.0f, lsq = 0.0f;
  const int hrow = wr*32 + v;
  char* const wp = wb + ((u*32)<<10) + (lane<<4);

#define SB() __builtin_amdgcn_sched_barrier(0)
#define GXS(KS, AR) { \
    half8 b0 = *(const half8*)(wp + ((0*8+KS)<<10)); \
    half8 b1 = *(const half8*)(wp + ((1*8+KS)<<10)); \
    half8 b2 = *(const half8*)(wp + ((2*8+KS)<<10)); \
    half8 b3 = *(const half8*)(wp + ((3*8+KS)<<10)); \
    acc0 = __builtin_amdgcn_mfma_f32_32x32x16_f16(AR, b0, acc0, 0,0,0); \
    acc1 = __builtin_amdgcn_mfma_f32_32x32x16_f16(AR, b1, acc1, 0,0,0); \
    acc2 = __builtin_amdgcn_mfma_f32_32x32x16_f16(AR, b2, acc2, 0,0,0); \
    acc3 = __builtin_amdgcn_mfma_f32_32x32x16_f16(AR, b3, acc3, 0,0,0); }
#define HXS(KS) { \
    half8 ah = *(const half8*)(hbr + ((hrow*256 + KS*32 + q*16) ^ ((hrow&15)<<4))); \
    half8 b0 = *(const half8*)(wp + ((0*8+KS)<<10)); \
    half8 b1 = *(const half8*)(wp + ((1*8+KS)<<10)); \
    half8 b2 = *(const half8*)(wp + ((2*8+KS)<<10)); \
    half8 b3 = *(const half8*)(wp + ((3*8+KS)<<10)); \
    acc0 = __builtin_amdgcn_mfma_f32_32x32x16_f16(ah, b0, acc0, 0,0,0); \
    acc1 = __builtin_amdgcn_mfma_f32_32x32x16_f16(ah, b1, acc1, 0,0,0); \
    acc2 = __builtin_amdgcn_mfma_f32_32x32x16_f16(ah, b2, acc2, 0,0,0); \
    acc3 = __builtin_amdgcn_mfma_f32_32x32x16_f16(ah, b3, acc3, 0,0,0); }
#define ACCI(CC) { \
    float g0 = bf[CC][0], g1 = bf[CC][1], g2 = bf[CC][2], g3 = bf[CC][3]; \
    _Pragma("unroll") for (int e=0;e<16;e++){ \
      acc0[e]=g0; acc1[e]=g1; acc2[e]=g2; acc3[e]=g3; } }
// fwd pointwise for chunk C, h-buffer HB, LAST accumulates LN partials
#define PWF(C, HB, LAST) { \
    const int ccol = C*64 + u*32 + v; \
    _Pragma("unroll") for (int e=0;e<16;e++){ \
      float iv = acc0[e], fv = acc1[e]; \
      float gv = acc2[e], ov = acc3[e]; \
      float cn = sigf(iv)*tanhf2(gv) + sigf(fv)*cst[C][e]; \
      cst[C][e] = cn; \
      float hv = sigf(ov)*tanhf2(cn); \
      _Float16 hh = (_Float16)hv; \
      int rl = wr*32 + (e&3) + ((e>>2)<<3) + (q<<2); \
      *(_Float16*)((HB) + ((rl*256 + ccol*2) ^ ((rl&15)<<4))) = hh; \
      if (LAST){ float hr = (float)hh; lsum += hr; lsq += hr*hr; } } }
// bwd pointwise (c0 = h0 = 0)
#define PWB(C, HB) { \
    const int ccol = C*64 + u*32 + v; \
    _Pragma("unroll") for (int e=0;e<16;e++){ \
      float iv = acc0[e]; \
      float gv = acc2[e], ov = acc3[e]; \
      float cn = sigf(iv)*tanhf2(gv); \
      float hv = sigf(ov)*tanhf2(cn); \
      _Float16 hh = (_Float16)hv; \
      int rl = wr*32 + (e&3) + ((e>>2)<<3) + (q<<2); \
      *(_Float16*)((HB) + ((rl*256 + ccol*2) ^ ((rl&15)<<4))) = hh; \
      float hr = (float)hh; lsum += hr; lsq += hr*hr; } }

  for (int t=0; t<len; ++t){
    const int chan = d_RIDX[r][t];
    if (XMODE){
      const _Float16* xp = x16 + (((size_t)bt*32 + chan)*4 + wr)*4096 + lane*8;
      xa0 = *(const half8*)(xp);          xa1 = *(const half8*)(xp + 512);
      xa2 = *(const half8*)(xp + 1024);   xa3 = *(const half8*)(xp + 1536);
      xa4 = *(const half8*)(xp + 2048);   xa5 = *(const half8*)(xp + 2560);
      xa6 = *(const half8*)(xp + 3072);   xa7 = *(const half8*)(xp + 3584);
    } else {
      const float* xb = xf32 + (((size_t)(b0 + wr*32 + v))*32 + chan)*128 + q*8;
      #define LXF(DST, OFF) { \
        float4 a0 = *(const float4*)(xb + OFF); \
        float4 a1 = *(const float4*)(xb + OFF + 4); \
        half8 a; \
        a[0]=(_Float16)a0.x; a[1]=(_Float16)a0.y; a[2]=(_Float16)a0.z; a[3]=(_Float16)a0.w; \
        a[4]=(_Float16)a1.x; a[5]=(_Float16)a1.y; a[6]=(_Float16)a1.z; a[7]=(_Float16)a1.w; \
        DST = a; }
      LXF(xa0,0) LXF(xa1,16) LXF(xa2,32) LXF(xa3,48)
      LXF(xa4,64) LXF(xa5,80) LXF(xa6,96) LXF(xa7,112)
      #undef LXF
    }
    const bool last = (t == len-1);
    char* hbr = hb0 + (((t+1)&1) << 15);   // h(t-1) buffer
    char* hbw = hb0 + ((t&1) << 15);       // h(t) buffer

    // ---- c = 0 : x-GEMM (deferred PW of prev t's c1 in this stage window) ----
    __syncthreads();                         // prior wb reads done
    stage_chunk(wih, r*4 + 0, wb, tid);
    if (t > 0) PWF(1, hbr, false)            // writes h(t-1), read at hGEMM below
    __syncthreads();
    ACCI(0)
    GXS(0,xa0) GXS(1,xa1) SB();
    GXS(2,xa2) GXS(3,xa3) SB();
    GXS(4,xa4) GXS(5,xa5) SB();
    GXS(6,xa6) GXS(7,xa7) SB();
    if (t > 0){
      __syncthreads();
      stage_chunk(whh, r*4 + 0, wb, tid);
      __syncthreads();
      HXS(0) HXS(1) SB();
      HXS(2) HXS(3) SB();
      HXS(4) HXS(5) SB();
      HXS(6) HXS(7) SB();
    }
    // ---- c = 1 : x-GEMM (PW(c0) of this t in stage window) ----
    __syncthreads();
    stage_chunk(wih, r*4 + 1, wb, tid);
    PWF(0, hbw, last)
    __syncthreads();
    ACCI(1)
    GXS(0,xa0) GXS(1,xa1) SB();
    GXS(2,xa2) GXS(3,xa3) SB();
    GXS(4,xa4) GXS(5,xa5) SB();
    GXS(6,xa6) GXS(7,xa7) SB();
    if (t > 0){
      __syncthreads();
      stage_chunk(whh, r*4 + 1, wb, tid);
      __syncthreads();
      HXS(0) HXS(1) SB();
      HXS(2) HXS(3) SB();
      HXS(4) HXS(5) SB();
      HXS(6) HXS(7) SB();
    }
    // c1 pointwise DEFERRED to next stage window
  }

  // ---- backward cell: h0=c0=0 -> gates = x_last*W_ih[:,1] + b. xa reused. ----
  {
    char* hfin = hb0 + (((len-1)&1) << 15);  // h(last) buffer (c1 half pending)
    char* hbk  = hb0 + ((len&1) << 15);      // bwd h buffer
    // c0:
    __syncthreads();
    stage_chunk(wih, r*4 + 2, wb, tid);
    PWF(1, hfin, true)                       // deferred last-t c1, with LN partials
    __syncthreads();
    {
      float g0 = bias[(size_t)r*1024 + 512 + 0*256 + u*128 + 0*32 + v];
      float g1 = bias[(size_t)r*1024 + 512 + 0*256 + u*128 + 1*32 + v];
      float g2 = bias[(size_t)r*1024 + 512 + 0*256 + u*128 + 2*32 + v];
      float g3 = bias[(size_t)r*1024 + 512 + 0*256 + u*128 + 3*32 + v];
      #pragma unroll
      for (int e=0;e<16;e++){ acc0[e]=g0; acc1[e]=g1; acc2[e]=g2; acc3[e]=g3; }
    }
    GXS(0,xa0) GXS(1,xa1) SB();
    GXS(2,xa2) GXS(3,xa3) SB();
    GXS(4,xa4) GXS(5,xa5) SB();
    GXS(6,xa6) GXS(7,xa7) SB();
    // c1:
    __syncthreads();
    stage_chunk(wih, r*4 + 3, wb, tid);
    PWB(0, hbk)
    __syncthreads();
    {
      float g0 = bias[(size_t)r*1024 + 512 + 1*256 + u*128 + 0*32 + v];
      float g1 = bias[(size_t)r*1024 + 512 + 1*256 + u*128 + 1*32 + v];
      float g2 = bias[(size_t)r*1024 + 512 + 1*256 + u*128 + 2*32 + v];
      float g3 = bias[(size_t)r*1024 + 512 + 1*256 + u*128 + 3*32 + v];
      #pragma unroll
      for (int e=0;e<16;e++){ acc0[e]=g0; acc1[e]=g1; acc2[e]=g2; acc3[e]=g3; }
    }
    GXS(0,xa0) GXS(1,xa1) SB();
    GXS(2,xa2) GXS(3,xa3) SB();
    GXS(4,xa4) GXS(5,xa5) SB();
    GXS(6,xa6) GXS(7,xa7) SB();
    PWB(1, hbk)
  }
#undef GXS
#undef HXS
#undef ACCI
#undef PWF
#undef PWB
#undef SB

  // ---- coalesced copy-out of fwd (hf) and bwd (hbk) h tiles ----
  __syncthreads();
  {
    const char* hf  = hb0 + (((len-1)&1) << 15);
    const char* hbk = hb0 + ((len&1) << 15);
    #pragma unroll
    for (int i=0;i<4;i++){
      int row = (tid>>4) + i*32;
      int bo  = (tid&15)*16;
      int lp  = row*256 + (bo ^ ((row&15)<<4));
      uint4 df = *(const uint4*)(hf + lp);
      uint4 db = *(const uint4*)(hbk + lp);
      size_t ob = ((size_t)(b0+row)*14 + r)*256;    // elems
      if (F16OUT){
        *(uint4*)((char*)hout + ob*2 + bo)       = df;   // fwd: bytes [0,256)
        *(uint4*)((char*)hout + ob*2 + 256 + bo) = db;   // bwd: bytes [256,512)
      } else {
        const _Float16* pf = (const _Float16*)&df;
        const _Float16* pb = (const _Float16*)&db;
        float* of  = fout + ob + (bo>>1);
        float* obw = fout + ob + 128 + (bo>>1);
        float4 o0, o1;
        o0.x=(float)pf[0]; o0.y=(float)pf[1]; o0.z=(float)pf[2]; o0.w=(float)pf[3];
        o1.x=(float)pf[4]; o1.y=(float)pf[5]; o1.z=(float)pf[6]; o1.w=(float)pf[7];
        *(float4*)of = o0; *(float4*)(of+4) = o1;
        o0.x=(float)pb[0]; o0.y=(float)pb[1]; o0.z=(float)pb[2]; o0.w=(float)pb[3];
        o1.x=(float)pb[4]; o1.y=(float)pb[5]; o1.z=(float)pb[6]; o1.w=(float)pb[7];
        *(float4*)obw = o0; *(float4*)(obw+4) = o1;
      }
    }
  }

  // ---- per-block partials ----
  #pragma unroll
  for (int off=32; off>0; off>>=1){
    lsum += __shfl_down(lsum, off);
    lsq  += __shfl_down(lsq, off);
  }
  __syncthreads();
  if (lane == 0){ red[wv] = lsum; red[8+wv] = lsq; }
  __syncthreads();
  if (tid == 0){
    float s = 0.0f, s2 = 0.0f;
    #pragma unroll
    for (int ww=0;ww<8;ww++){ s += red[ww]; s2 += red[8+ww]; }
    part[((size_t)r*64 + bt)*2]     = s;
    part[((size_t)r*64 + bt)*2 + 1] = s2;
  }
}

// ---------------------------------------------------------------------------
__global__ void stats_k(const float* __restrict__ part, const float* __restrict__ gamma,
                        const float* __restrict__ beta, float* __restrict__ stat)
{
  int r = blockIdx.x, l = threadIdx.x;
  float s  = part[((size_t)r*64 + l)*2];
  float s2 = part[((size_t)r*64 + l)*2 + 1];
  #pragma unroll
  for (int off=32; off>0; off>>=1){ s += __shfl_down(s, off); s2 += __shfl_down(s2, off); }
  if (l == 0){
    const float cnt = 2097152.0f;
    float m = s / cnt;
    float var = s2 / cnt - m*m;
    float rstd = rsqrtf(var + 1e-5f);
    float sc = gamma[r]*rstd;
    stat[r*2]   = sc;
    stat[r*2+1] = beta[r] - m*sc;
  }
}

__global__ void apply_f16(const _Float16* __restrict__ hst, const float* __restrict__ stat,
                          float* __restrict__ out)
{
  size_t i8 = (size_t)blockIdx.x*256 + threadIdx.x;
  uint4 vv = *(const uint4*)(hst + i8*8);
  int r = (int)((i8 >> 5) % 14);
  float sc = stat[r*2], sh = stat[r*2+1];
  const _Float16* hp = (const _Float16*)&vv;
  float4 o0, o1;
  o0.x = (float)hp[0]*sc + sh; o0.y = (float)hp[1]*sc + sh;
  o0.z = (float)hp[2]*sc + sh; o0.w = (float)hp[3]*sc + sh;
  o1.x = (float)hp[4]*sc + sh; o1.y = (float)hp[5]*sc + sh;
  o1.z = (float)hp[6]*sc + sh; o1.w = (float)hp[7]*sc + sh;
  ((float4*)out)[i8*2]     = o0;
  ((float4*)out)[i8*2 + 1] = o1;
}

__global__ void apply_f32(float* __restrict__ out, const float* __restrict__ stat)
{
  size_t idx = (size_t)blockIdx.x*256 + threadIdx.x;
  float4* p = (float4*)out + idx;
  float4 vv = *p;
  int r = (int)((idx >> 6) % 14);
  float sc = stat[r*2], sh = stat[r*2+1];
  vv.x = vv.x*sc + sh; vv.y = vv.y*sc + sh; vv.z = vv.z*sc + sh; vv.w = vv.w*sc + sh;
  *p = vv;
}

// ---------------------------------------------------------------------------
extern "C" void kernel_launch(void* const* d_in, const int* in_sizes, int n_in,
                              void* d_out, int out_size, void* d_ws, size_t ws_size,
                              hipStream_t stream)
{
  const float* x     = (const float*)d_in[0];
  const float* w_ih  = (const float*)d_in[1];
  const float* w_hh  = (const float*)d_in[2];
  const float* b_ih  = (const float*)d_in[3];
  const float* b_hh  = (const float*)d_in[4];
  const float* gamma = (const float*)d_in[5];
  const float* beta  = (const float*)d_in[6];
  float* out = (float*)d_out;

  const size_t HS = 29360128;               // h elements (B*14*256)
  const size_t XS = 33554432;               // x elements (B*32*128)
  const size_t wbytes = (size_t)1835008*2;  // one weight array, bytes
  const size_t tail = (14336 + 1792 + 28)*4;
  const size_t need_full = XS*2 + HS*2 + 2*wbytes + tail;   // ~138 MB

  char* wsp = (char*)d_ws;
  int full = (ws_size >= need_full) ? 1 : 0;

  _Float16* x16p; _Float16* hstore; _Float16* wihp;
  if (full){
    x16p   = (_Float16*)wsp;
    hstore = (_Float16*)(wsp + XS*2);
    wihp   = (_Float16*)(wsp + XS*2 + HS*2);
  } else {
    x16p   = (_Float16*)wsp;  // unused
    hstore = (_Float16*)wsp;  // unused
    wihp   = (_Float16*)wsp;
  }
  _Float16* whhp = wihp + 1835008;
  float* biasp = (float*)(whhp + 1835008);
  float* partp = biasp + 14336;
  float* statp = partp + 1792;

  prep_w<<<1848, 256, 0, stream>>>(w_ih, w_hh, b_ih, b_hh, wihp, whhp, biasp);
  if (full){
    prep_x<<<16384, 256, 0, stream>>>(x, x16p);
    lstm_k<1,1><<<1024, 512, 0, stream>>>(x, x16p, wihp, whhp, biasp,
                                          hstore, out, partp);
  } else {
    lstm_k<0,0><<<1024, 512, 0, stream>>>(x, x16p, wihp, whhp, biasp,
                                          hstore, out, partp);
  }
  stats_k<<<14, 64, 0, stream>>>(partp, gamma, beta, statp);
  if (full)
    apply_f16<<<14336, 256, 0, stream>>>(hstore, statp, out);
  else
    apply_f32<<<28672, 256, 0, stream>>>(out, statp);
}